// Round 18
// baseline (450.225 us; speedup 1.0000x reference)
//
#include <hip/hip_runtime.h>
#include <hip/hip_bf16.h>
#include <math.h>

// Dynamic_MHGCN_FusionLayer: B=256, N=131, IN=512, OUT=1024, H=4, D=256
// Round 18: edge_agg register diet to unlock 2 blocks/CU (<=102 regs/wave):
// e spilled to LDS bf16 in-place in the Wb buffer; adj re-read from L2 in the
// Wb pass (areg dropped); phase-4 aggregation in 2 d-passes (gacc halved);
// __launch_bounds__(576,5). Rest = R17 (389us best).

#define LRELU(x) ((x) > 0.f ? (x) : 0.01f * (x))

constexpr int Bb = 256;
constexpr int Nn = 131;
constexpr int INF_ = 512;
constexpr int OUTF = 1024;
constexpr int Hh = 4;
constexpr int Dd = 256;
constexpr int OC2 = 2048;  // Gcat: Gk(0..1023) | Gq(1024..2047)
constexpr int YP = 168;    // GrawT row stride (shorts)
constexpr int WLP = 174;   // WbL/eL LDS row stride (shorts): odd dwords -> conflict-free
constexpr int KAGG = 160;

typedef __attribute__((ext_vector_type(8))) short bf16x8;
typedef __attribute__((ext_vector_type(4))) float f32x4;

__device__ __forceinline__ float bf2f(short s) {
    union { float f; unsigned u; } c;
    c.u = ((unsigned)(unsigned short)s) << 16;
    return c.f;
}

__device__ __forceinline__ void gload_lds16(const void* g, void* lds) {
    __builtin_amdgcn_global_load_lds(
        (const __attribute__((address_space(1))) void*)g,
        (__attribute__((address_space(3))) void*)lds, 16, 0, 0);
}

// ---------------------------------------------------------------------------
// fp32 -> bf16 conversion. Wcat packed as [Wgk | Wgq | Wgx] (3072 x 512).
// ---------------------------------------------------------------------------
__global__ __launch_bounds__(256) void convert_kernel(
    const float* __restrict__ node, const float* __restrict__ Wgx,
    const float* __restrict__ Wgk, const float* __restrict__ Wgq,
    __hip_bfloat16* __restrict__ node_bf, __hip_bfloat16* __restrict__ Wcat)
{
    const size_t NE = (size_t)Bb * Nn * INF_ / 4;
    const size_t WE = (size_t)3072 * INF_ / 4;
    for (size_t i = (size_t)blockIdx.x * 256 + threadIdx.x; i < NE + WE;
         i += (size_t)gridDim.x * 256) {
        if (i < NE) {
            const float4 v = ((const float4*)node)[i];
            __hip_bfloat16* o = node_bf + i * 4;
            o[0] = __float2bfloat16(v.x); o[1] = __float2bfloat16(v.y);
            o[2] = __float2bfloat16(v.z); o[3] = __float2bfloat16(v.w);
        } else {
            const size_t j = i - NE;
            const size_t which = j / (1024 * INF_ / 4);
            const float* src = (which == 0) ? Wgk : (which == 1 ? Wgq : Wgx);
            const size_t srcj = j - which * (1024 * INF_ / 4);
            const float4 v = ((const float4*)src)[srcj];
            __hip_bfloat16* o = Wcat + j * 4;
            o[0] = __float2bfloat16(v.x); o[1] = __float2bfloat16(v.y);
            o[2] = __float2bfloat16(v.z); o[3] = __float2bfloat16(v.w);
        }
    }
}

// ---------------------------------------------------------------------------
// Fused node GEMM (bf16 MFMA): 128x128 tile, 4 waves (2x2), BK=64 single
// buffer, XOR granule swizzle (0 bank conflicts).
// o-tiles 0..7  (Gk):  row-major stores + node-att score partials -> spart.
// o-tiles 8..15 (Gq):  row-major stores.
// o-tiles 16..23 (Graw): lrelu(.+b_gx) transposed via LDS -> GrawT (coalesced).
// ---------------------------------------------------------------------------
__global__ __launch_bounds__(256, 4) void gemm_node_mfma(
    const __hip_bfloat16* __restrict__ A, const __hip_bfloat16* __restrict__ W,
    const float* __restrict__ bias_gx, const float* __restrict__ Tq,
    __hip_bfloat16* __restrict__ Gcat, __hip_bfloat16* __restrict__ GrawT,
    float* __restrict__ spart)
{
    __shared__ short SM[16384];          // As=[0,8192), Bs=[8192,16384)
    short* As = SM;
    short* Bs = SM + 8192;
    const int tid = threadIdx.x;
    const int wave = tid >> 6, lane = tid & 63;
    const int m0 = blockIdx.y * 128, o0 = blockIdx.x * 128;
    const int wr = wave >> 1, wc = wave & 1;

    f32x4 acc[4][4] = {};
    const short* Asrc = (const short*)A;
    const short* Wsrc = (const short*)W;
    const int gsrc = ((tid & 7) ^ ((tid >> 3) & 7)) * 8;
    const int srow = tid >> 3;

    for (int kt = 0; kt < 8; ++kt) {
        const int k0 = kt * 64;
        #pragma unroll
        for (int j = 0; j < 4; ++j) {
            const int row = j * 32 + srow;
            gload_lds16(Asrc + (size_t)(m0 + row) * INF_ + k0 + gsrc,
                        &As[(j * 256 + (tid & ~63)) * 8]);
            gload_lds16(Wsrc + (size_t)(o0 + row) * INF_ + k0 + gsrc,
                        &Bs[(j * 256 + (tid & ~63)) * 8]);
        }
        __syncthreads();
        #pragma unroll
        for (int ks = 0; ks < 2; ++ks) {
            const int sa = ((ks * 4 + (lane >> 4)) ^ (lane & 7)) * 8;
            bf16x8 af[4], bfr[4];
            #pragma unroll
            for (int i = 0; i < 4; ++i) {
                af[i]  = *(const bf16x8*)&As[(wr * 64 + i * 16 + (lane & 15)) * 64 + sa];
                bfr[i] = *(const bf16x8*)&Bs[(wc * 64 + i * 16 + (lane & 15)) * 64 + sa];
            }
            #pragma unroll
            for (int mi = 0; mi < 4; ++mi)
                #pragma unroll
                for (int ni = 0; ni < 4; ++ni)
                    acc[mi][ni] = __builtin_amdgcn_mfma_f32_16x16x32_bf16(
                        af[mi], bfr[ni], acc[mi][ni], 0, 0, 0);
        }
        __syncthreads();
    }

    const int cc = lane & 15;
    const int rg = (lane >> 4) * 4;
    if (o0 < 1024) {
        // Gk tile: stores + node-att score partials
        const int blo = m0 / 131;
        const int msw = (blo + 1) * 131;
        float tqA[4], tqB[4];
        #pragma unroll
        for (int ni = 0; ni < 4; ++ni) {
            const int o = o0 + wc * 64 + ni * 16 + cc;
            tqA[ni] = Tq[(size_t)blo * OUTF + o];
            tqB[ni] = (blo + 1 < Bb) ? Tq[(size_t)(blo + 1) * OUTF + o] : 0.f;
        }
        float sc[4][4] = {};
        #pragma unroll
        for (int mi = 0; mi < 4; ++mi)
            #pragma unroll
            for (int ni = 0; ni < 4; ++ni) {
                const int o = o0 + wc * 64 + ni * 16 + cc;
                #pragma unroll
                for (int r = 0; r < 4; ++r) {
                    const int m = m0 + wr * 64 + mi * 16 + rg + r;
                    float v = acc[mi][ni][r];
                    v = LRELU(v);
                    Gcat[(size_t)m * OC2 + o] = __float2bfloat16(v);
                    sc[mi][r] += v * ((m >= msw) ? tqB[ni] : tqA[ni]);
                }
            }
        const int slot = (o0 >> 6) + wc;
        #pragma unroll
        for (int mi = 0; mi < 4; ++mi)
            #pragma unroll
            for (int r = 0; r < 4; ++r) {
                float s = sc[mi][r];
                s += __shfl_xor(s, 1); s += __shfl_xor(s, 2);
                s += __shfl_xor(s, 4); s += __shfl_xor(s, 8);
                if (cc == 0) {
                    const int m = m0 + wr * 64 + mi * 16 + rg + r;
                    spart[(size_t)m * 16 + slot] = s;
                }
            }
    } else if (o0 < OC2) {
        // Gq tile: plain row-major stores
        #pragma unroll
        for (int mi = 0; mi < 4; ++mi)
            #pragma unroll
            for (int ni = 0; ni < 4; ++ni) {
                const int o = o0 + wc * 64 + ni * 16 + cc;
                #pragma unroll
                for (int r = 0; r < 4; ++r) {
                    const int m = m0 + wr * 64 + mi * 16 + rg + r;
                    float v = acc[mi][ni][r];
                    v = LRELU(v);
                    Gcat[(size_t)m * OC2 + o] = __float2bfloat16(v);
                }
            }
    } else {
        // Graw tile: lrelu(.+b_gx); transposed via LDS, coalesced 16B stores
        const int og0 = o0 - OC2;
        const int h = og0 >> 8;
        const int dbase = og0 & 255;
        __syncthreads();
        #pragma unroll
        for (int mi = 0; mi < 4; ++mi)
            #pragma unroll
            for (int ni = 0; ni < 4; ++ni) {
                const int dloc = wc * 64 + ni * 16 + cc;
                const float badd = bias_gx[og0 + dloc];
                #pragma unroll
                for (int r = 0; r < 4; ++r) {
                    const int row = wr * 64 + mi * 16 + rg + r;
                    float v = acc[mi][ni][r] + badd;
                    v = LRELU(v);
                    __hip_bfloat16 hb = __float2bfloat16(v);
                    const int g = row >> 3;
                    SM[dloc * 128 + ((g ^ (dloc & 7)) << 3) + (row & 7)] = *(short*)&hb;
                }
            }
        __syncthreads();
        short* GT = (short*)GrawT;
        #pragma unroll
        for (int j = 0; j < 8; ++j) {
            const int task = j * 256 + tid;
            const int dloc = task >> 4;
            const int g = task & 15;
            const bf16x8 v = *(const bf16x8*)&SM[dloc * 128 + ((g ^ (dloc & 7)) << 3)];
            const int m = m0 + g * 8;
            const int gd = dbase + dloc;
            const int b0 = m / 131;
            const int n0 = m - b0 * 131;
            if (n0 + 8 <= Nn) {
                *(bf16x8*)&GT[((size_t)(b0 * Hh + h) * 256 + gd) * YP + n0] = v;
            } else {
                #pragma unroll
                for (int e = 0; e < 8; ++e) {
                    const int mm = m + e;
                    const int bb = mm / 131;
                    const int nn = mm - bb * 131;
                    GT[((size_t)(bb * Hh + h) * 256 + gd) * YP + nn] = ((const short*)&v)[e];
                }
            }
        }
    }
}

// ---------------------------------------------------------------------------
// Merged tabular GEMMs (fp32): which=0 -> T_X (bias b_tx), which=1 -> T_q.
// ---------------------------------------------------------------------------
__global__ __launch_bounds__(256) void gemm_tab(
    const float* __restrict__ Atab, const float* __restrict__ Wtx,
    const float* __restrict__ btx, const float* __restrict__ Wtq,
    float* __restrict__ Ctx, float* __restrict__ Ctq)
{
    const int which = blockIdx.x >> 4;
    const float* Wm = which ? Wtq : Wtx;
    float* C = which ? Ctq : Ctx;
    __shared__ float As[16][68];
    __shared__ float Ws[16][68];
    const int tid = threadIdx.x;
    const int tx = tid & 15;
    const int ty = tid >> 4;
    const int m0 = blockIdx.y * 64;
    const int o0 = (blockIdx.x & 15) * 64;

    float acc[4][4] = {};
    for (int k0 = 0; k0 < INF_; k0 += 16) {
        const int j = tid & 15;
        const int i = tid >> 4;
        #pragma unroll
        for (int r = 0; r < 4; ++r)
            As[j][i + 16 * r] = Atab[(size_t)(m0 + i + 16 * r) * INF_ + k0 + j];
        #pragma unroll
        for (int r = 0; r < 4; ++r)
            Ws[j][i + 16 * r] = Wm[(size_t)(o0 + i + 16 * r) * INF_ + k0 + j];
        __syncthreads();
        #pragma unroll
        for (int kk = 0; kk < 16; ++kk) {
            const float4 av = *(const float4*)&As[kk][ty * 4];
            const float4 wv = *(const float4*)&Ws[kk][tx * 4];
            const float a[4] = {av.x, av.y, av.z, av.w};
            const float w[4] = {wv.x, wv.y, wv.z, wv.w};
            #pragma unroll
            for (int r = 0; r < 4; ++r)
                #pragma unroll
                for (int c = 0; c < 4; ++c)
                    acc[r][c] += a[r] * w[c];
        }
        __syncthreads();
    }
    #pragma unroll
    for (int r = 0; r < 4; ++r) {
        const int m = m0 + ty * 4 + r;
        const int o = o0 + tx * 4;
        float4 v;
        float* vp = (float*)&v;
        #pragma unroll
        for (int c = 0; c < 4; ++c) {
            float t = acc[r][c] + (which ? 0.f : btx[o + c]);
            vp[c] = LRELU(t);
        }
        *(float4*)&C[(size_t)m * OUTF + o] = v;
    }
}

// ---------------------------------------------------------------------------
// Zin build: Zin[b][0:1024] = lrelu(gnode + bgs), Zin[b][1024:2048] = T_X.
// ---------------------------------------------------------------------------
__global__ __launch_bounds__(256) void zin_build(
    const float* __restrict__ gnode, const float* __restrict__ bgs,
    const float* __restrict__ Tx, float* __restrict__ Zin)
{
    const int idx = blockIdx.x * 256 + threadIdx.x;
    const int b = idx >> 10, o = idx & 1023;
    const float s = gnode[idx] + bgs[0];
    Zin[(size_t)b * 2048 + o] = LRELU(s);
    Zin[(size_t)b * 2048 + 1024 + o] = Tx[idx];
}

// ---------------------------------------------------------------------------
// Z GEMM split-K: grid (16,4,4); chunk kz covers K in [kz*512,(kz+1)*512).
// ---------------------------------------------------------------------------
__global__ __launch_bounds__(256) void gemm_zsplit(
    const float* __restrict__ A, const float* __restrict__ W,
    float* __restrict__ P)
{
    __shared__ float As[16][68];
    __shared__ float Ws[16][68];
    const int tid = threadIdx.x;
    const int tx = tid & 15;
    const int ty = tid >> 4;
    const int m0 = blockIdx.y * 64;
    const int o0 = blockIdx.x * 64;
    const int kbase = blockIdx.z * 512;

    float acc[4][4] = {};
    for (int k0 = kbase; k0 < kbase + 512; k0 += 16) {
        const int j = tid & 15;
        const int i = tid >> 4;
        #pragma unroll
        for (int r = 0; r < 4; ++r)
            As[j][i + 16 * r] = A[(size_t)(m0 + i + 16 * r) * 2048 + k0 + j];
        #pragma unroll
        for (int r = 0; r < 4; ++r)
            Ws[j][i + 16 * r] = W[(size_t)(o0 + i + 16 * r) * 2048 + k0 + j];
        __syncthreads();
        #pragma unroll
        for (int kk = 0; kk < 16; ++kk) {
            const float4 av = *(const float4*)&As[kk][ty * 4];
            const float4 wv = *(const float4*)&Ws[kk][tx * 4];
            const float a[4] = {av.x, av.y, av.z, av.w};
            const float w[4] = {wv.x, wv.y, wv.z, wv.w};
            #pragma unroll
            for (int r = 0; r < 4; ++r)
                #pragma unroll
                for (int c = 0; c < 4; ++c)
                    acc[r][c] += a[r] * w[c];
        }
        __syncthreads();
    }
    float* pz = P + (size_t)blockIdx.z * Bb * OUTF;
    #pragma unroll
    for (int r = 0; r < 4; ++r) {
        const int m = m0 + ty * 4 + r;
        const int o = o0 + tx * 4;
        float4 v;
        float* vp = (float*)&v;
        #pragma unroll
        for (int c = 0; c < 4; ++c) vp[c] = acc[r][c];
        *(float4*)&pz[(size_t)m * OUTF + o] = v;
    }
}

// ---------------------------------------------------------------------------
// Z reduce: C = lrelu(sum_4 P + bzx).
// ---------------------------------------------------------------------------
__global__ __launch_bounds__(256) void zreduce(
    const float* __restrict__ P, const float* __restrict__ bzx,
    float* __restrict__ C)
{
    const int idx = blockIdx.x * 256 + threadIdx.x;
    const int o = idx & 1023;
    const size_t STRIDE = (size_t)Bb * OUTF;
    float s = P[idx] + P[STRIDE + idx] + P[2 * STRIDE + idx] + P[3 * STRIDE + idx]
            + bzx[o];
    C[idx] = LRELU(s);
}

// ---------------------------------------------------------------------------
// nodeatt_soft: s[b,n] = (1/32) * sum_16 spart[(b*131+n)][slot]; softmax; +1.
// ---------------------------------------------------------------------------
__global__ __launch_bounds__(256) void nodeatt_soft(
    const float* __restrict__ spart, float* __restrict__ att)
{
    const int b = blockIdx.x;
    __shared__ float sc[136];
    const int tid = threadIdx.x;
    if (tid < Nn) {
        const float* sp = spart + (size_t)(b * Nn + tid) * 16;
        float s = 0.f;
        #pragma unroll
        for (int i = 0; i < 16; ++i) s += sp[i];
        sc[tid] = s * (1.f / 32.f);
    }
    __syncthreads();
    if (tid < 64) {
        const float v1 = sc[tid];
        const float v2 = sc[tid + 64];
        const float v3 = (tid < 3) ? sc[tid + 128] : -1e30f;
        float m = fmaxf(fmaxf(v1, v2), v3);
        #pragma unroll
        for (int off = 32; off; off >>= 1) m = fmaxf(m, __shfl_xor(m, off));
        const float e1 = expf(v1 - m);
        const float e2 = expf(v2 - m);
        const float e3 = (tid < 3) ? expf(v3 - m) : 0.f;
        float s = e1 + e2 + e3;
        #pragma unroll
        for (int off = 32; off; off >>= 1) s += __shfl_xor(s, off);
        const float inv = 1.f / s;
        float* ab = att + (size_t)b * Nn;
        ab[tid] = e1 * inv + 1.f;
        ab[tid + 64] = e2 * inv + 1.f;
        if (tid < 3) ab[tid + 128] = e3 * inv + 1.f;
    }
}

// ---------------------------------------------------------------------------
// edge_agg (register diet): one block (9 waves) per (b,h).
// Phase 1: QK^T via MFMA (Q/K dbuf, counted vmcnt, XOR swizzle).
// Phase 2: sigmoid -> e; edge write (fp32); e -> LDS bf16 (eL, stride WLP);
//          adj L2 read for rowsums; dinv.
// Phase 3: in-place eL -> Wb (adj re-read from L2; thread-owned slots).
// Phase 4: aggregation MFMA in TWO d-passes (gacc[9] per pass).
// Phase 5: Gout + gnode colsum per pass.
// __launch_bounds__(576,5): cap regs ~102 -> 2 blocks/CU.
// ---------------------------------------------------------------------------
__global__ __launch_bounds__(576, 5) void edge_agg(
    const __hip_bfloat16* __restrict__ Gcat, const float* __restrict__ adj,
    const float* __restrict__ att, const __hip_bfloat16* __restrict__ GrawT,
    const float* __restrict__ Wgs, float* __restrict__ edge,
    float* __restrict__ Gout, float* __restrict__ gnode)
{
    __shared__ short SM[25056];          // phase1: Q/K dbuf [0,18432); then eL/WbL
    __shared__ float rsL[144 * 3];
    __shared__ float dxL[Nn], daL[Nn], attL[Nn], wgsL[Nn];

    const int bh = blockIdx.x, b = bh >> 2, h = bh & 3;
    const int tid = threadIdx.x;
    const int lane = tid & 63, wid = tid >> 6;
    const int wr = wid / 3, wc = wid % 3;
    if (tid < Nn) { attL[tid] = att[(size_t)b * Nn + tid]; wgsL[tid] = Wgs[tid]; }

    const short* qb = (const short*)Gcat + (size_t)b * Nn * OC2 + 1024 + h * Dd;
    const short* kb = (const short*)Gcat + (size_t)b * Nn * OC2 + h * Dd;
    const short* gsrcT = (const short*)GrawT + (size_t)bh * 256 * YP;

    int srow = tid >> 2; if (srow > Nn - 1) srow = Nn - 1;
    const int gsrc = ((tid & 3) ^ ((tid >> 3) & 3)) * 8;
    const int dstoff = (tid & ~63) * 8;

    auto STAGE = [&](int buf, int k0) {
        gload_lds16(qb + (size_t)srow * OC2 + k0 + gsrc, &SM[buf * 4608 + dstoff]);
        gload_lds16(kb + (size_t)srow * OC2 + k0 + gsrc, &SM[9216 + buf * 4608 + dstoff]);
    };

    f32x4 acc[3][3] = {};
    const int sa = ((lane >> 4) ^ ((lane >> 1) & 3)) * 8;

    STAGE(0, 0);
    for (int t = 0; t < 8; ++t) {
        const int buf = t & 1;
        if (t < 7) {
            STAGE(buf ^ 1, (t + 1) * 32);
            asm volatile("s_waitcnt vmcnt(2)" ::: "memory");
        } else {
            asm volatile("s_waitcnt vmcnt(0)" ::: "memory");
        }
        __builtin_amdgcn_s_barrier();
        __builtin_amdgcn_sched_barrier(0);
        bf16x8 qf[3], kf[3];
        #pragma unroll
        for (int i = 0; i < 3; ++i) {
            qf[i] = *(const bf16x8*)&SM[buf * 4608 + (wr * 48 + i * 16 + (lane & 15)) * 32 + sa];
            kf[i] = *(const bf16x8*)&SM[9216 + buf * 4608 + (wc * 48 + i * 16 + (lane & 15)) * 32 + sa];
        }
        __builtin_amdgcn_s_setprio(1);
        #pragma unroll
        for (int mi = 0; mi < 3; ++mi)
            #pragma unroll
            for (int ni = 0; ni < 3; ++ni)
                acc[mi][ni] = __builtin_amdgcn_mfma_f32_16x16x32_bf16(
                    qf[mi], kf[ni], acc[mi][ni], 0, 0, 0);
        __builtin_amdgcn_s_setprio(0);
        __builtin_amdgcn_sched_barrier(0);
        if (t < 7) __builtin_amdgcn_s_barrier();
    }
    __syncthreads();   // all QK^T SM reads done -> safe to overwrite with eL

    // phase 2: sigmoid -> e; edge write; e -> eL (bf16); rowsums (adj from L2)
    const float* adjb = adj + (size_t)b * Nn * Nn;
    float* edgeb = edge + (size_t)bh * Nn * Nn;
    const int cc = lane & 15;
    const int rg = (lane >> 4) * 4;
    short* eL = SM;     // [144][WLP]
    #pragma unroll
    for (int mi = 0; mi < 3; ++mi) {
        float rsum[4] = {0.f, 0.f, 0.f, 0.f};
        #pragma unroll
        for (int ni = 0; ni < 3; ++ni) {
            const int y = wc * 48 + ni * 16 + cc;
            #pragma unroll
            for (int r = 0; r < 4; ++r) {
                const int x = wr * 48 + mi * 16 + rg + r;
                const bool in = (x < Nn) && (y < Nn);
                const float e = 1.f / (1.f + __expf(-acc[mi][ni][r] * (1.f / 16.f)));
                float ew = 0.f;
                if (in) {
                    edgeb[x * Nn + y] = e;
                    rsum[r] += adjb[x * Nn + y] * e;
                    ew = e;
                }
                __hip_bfloat16 he = __float2bfloat16(ew);
                eL[x * WLP + y] = *(short*)&he;
            }
        }
        #pragma unroll
        for (int r = 0; r < 4; ++r) {
            float v = rsum[r];
            v += __shfl_xor(v, 1); v += __shfl_xor(v, 2);
            v += __shfl_xor(v, 4); v += __shfl_xor(v, 8);
            const int x = wr * 48 + mi * 16 + rg + r;
            if (cc == 0 && x < Nn) rsL[x * 3 + wc] = v;
        }
    }
    // zero pad strip y in [144,160) (cols beyond wave tiles, read by agg)
    for (int i = tid; i < 144 * 16; i += 576) {
        const int x = i >> 4, y = 144 + (i & 15);
        eL[x * WLP + y] = 0;
    }
    __syncthreads();
    if (tid < Nn) {
        const float s = rsL[tid * 3] + rsL[tid * 3 + 1] + rsL[tid * 3 + 2];
        const float dv = rsqrtf(s + 1.f);
        dxL[tid] = dv;
        daL[tid] = dv * attL[tid];
    }
    __syncthreads();

    // phase 3: in-place eL -> Wb (thread-owned slots; adj re-read, L2-hot)
    #pragma unroll
    for (int mi = 0; mi < 3; ++mi)
        #pragma unroll
        for (int ni = 0; ni < 3; ++ni) {
            const int y = wc * 48 + ni * 16 + cc;
            #pragma unroll
            for (int r = 0; r < 4; ++r) {
                const int x = wr * 48 + mi * 16 + rg + r;
                float w = 0.f;
                if (x < Nn && y < Nn) {
                    float a = adjb[x * Nn + y] * bf2f(eL[x * WLP + y]);
                    if (x == y) a += 1.f;
                    w = dxL[x] * a * daL[y];
                }
                __hip_bfloat16 hb = __float2bfloat16(w);
                eL[x * WLP + y] = *(short*)&hb;
            }
        }
    __syncthreads();   // WbL visible to all waves

    // phase 4+5: aggregation MFMA in 2 d-passes + epilogue
    const short* WbL = SM;
    if (wid < 8) {
        float* gob = Gout + (size_t)b * Nn * OUTF + h * Dd;
        const int bcol = (lane >> 4) * 8;
        #pragma unroll
        for (int ni = 0; ni < 2; ++ni) {
            const int brow = wid * 32 + ni * 16 + (lane & 15);
            f32x4 gacc[9] = {};
            #pragma unroll 1
            for (int kc = 0; kc < 5; ++kc) {
                const bf16x8 bfr = *(const bf16x8*)&gsrcT[(size_t)brow * YP + kc * 32 + bcol];
                bf16x8 af[9];
                #pragma unroll
                for (int mi = 0; mi < 9; ++mi)
                    af[mi] = *(const bf16x8*)&WbL[(mi * 16 + (lane & 15)) * WLP + kc * 32 + (lane >> 4) * 8];
                __builtin_amdgcn_s_setprio(1);
                #pragma unroll
                for (int mi = 0; mi < 9; ++mi)
                    gacc[mi] = __builtin_amdgcn_mfma_f32_16x16x32_bf16(
                        af[mi], bfr, gacc[mi], 0, 0, 0);
                __builtin_amdgcn_s_setprio(0);
            }
            const int d = wid * 32 + ni * 16 + (lane & 15);
            float gp = 0.f;
            #pragma unroll
            for (int mi = 0; mi < 9; ++mi)
                #pragma unroll
                for (int r = 0; r < 4; ++r) {
                    const int x = mi * 16 + (lane >> 4) * 4 + r;
                    if (x < Nn) {
                        gob[(size_t)x * OUTF + d] = gacc[mi][r];
                        gp += wgsL[x] * gacc[mi][r];
                    }
                }
            gp += __shfl_xor(gp, 16);
            gp += __shfl_xor(gp, 32);
            if (lane < 16)
                gnode[(size_t)b * OUTF + h * Dd + d] = gp;
        }
    }
}

// ---------------------------------------------------------------------------
extern "C" void kernel_launch(void* const* d_in, const int* in_sizes, int n_in,
                              void* d_out, int out_size, void* d_ws, size_t ws_size,
                              hipStream_t stream) {
    const float* tab  = (const float*)d_in[0];
    const float* node = (const float*)d_in[1];
    const float* adj  = (const float*)d_in[2];
    const float* W_gx = (const float*)d_in[3];
    const float* b_gx = (const float*)d_in[4];
    const float* W_tx = (const float*)d_in[5];
    const float* b_tx = (const float*)d_in[6];
    const float* W_gk = (const float*)d_in[7];
    const float* W_tq = (const float*)d_in[8];
    const float* W_gq = (const float*)d_in[9];
    const float* W_gs = (const float*)d_in[10];
    const float* b_gs = (const float*)d_in[11];
    const float* W_zx = (const float*)d_in[12];
    const float* b_zx = (const float*)d_in[13];

    const size_t GX_ELEMS = (size_t)Bb * Nn * OUTF;   // 34,340,864
    const int M_NODE = Bb * Nn;                       // 33536

    float* out   = (float*)d_out;
    float* o_GX  = out;
    float* o_TX  = o_GX + GX_ELEMS;
    float* o_ZX  = o_TX + (size_t)Bb * OUTF;
    float* o_ATT = o_ZX + (size_t)Bb * OUTF;
    float* o_EDG = o_ATT + (size_t)Bb * Nn;

    // workspace: bf16 regions first, then fp32
    __hip_bfloat16* wb      = (__hip_bfloat16*)d_ws;
    __hip_bfloat16* w_nodeb = wb;                                          // 33536*512
    __hip_bfloat16* w_Wcat  = w_nodeb + (size_t)M_NODE * INF_;             // 3072*512
    __hip_bfloat16* w_Gcat  = w_Wcat + (size_t)3072 * INF_;                // 33536*2048
    __hip_bfloat16* w_GrawT = w_Gcat + (size_t)M_NODE * OC2;               // 1024*256*168
    float* wf       = (float*)(w_GrawT + (size_t)Bb * Hh * 256 * YP);
    float* w_Tq     = wf;
    float* w_Zin    = w_Tq + (size_t)Bb * OUTF;                            // 256*2048
    float* w_gnode  = w_Zin + (size_t)Bb * 2 * OUTF;                       // 256*1024
    float* w_spart  = w_gnode + (size_t)Bb * OUTF;                         // 33536*16
    float* w_zpart  = w_spart + (size_t)M_NODE * 16;                       // 4*256*1024

    const dim3 blk(256);

    // 0. fp32 -> bf16 (Wcat = [Wgk | Wgq | Wgx])
    convert_kernel<<<dim3(2048), blk, 0, stream>>>(node, W_gx, W_gk, W_gq,
                                                   w_nodeb, w_Wcat);
    // 1. merged tabular GEMMs (T_X + T_q)
    gemm_tab<<<dim3(32, 4), blk, 0, stream>>>(tab, W_tx, b_tx, W_tq, o_TX, w_Tq);
    // 2. fused node GEMM -> Gcat + GrawT + node-att score partials
    gemm_node_mfma<<<dim3(24, M_NODE / 128), blk, 0, stream>>>(
        w_nodeb, w_Wcat, b_gx, w_Tq, w_Gcat, w_GrawT, w_spart);
    // 3. node attention softmax (from partials) -> o_ATT
    nodeatt_soft<<<dim3(Bb), blk, 0, stream>>>(w_spart, o_ATT);
    // 4. fused edge attention + rowsum + dinv + Wb(LDS) + aggregation + gn
    edge_agg<<<dim3(Bb * Hh), dim3(576), 0, stream>>>(
        w_Gcat, adj, o_ATT, w_GrawT, W_gs, o_EDG, o_GX, w_gnode);
    // 5. Zin build
    zin_build<<<dim3((Bb * OUTF) / 256), blk, 0, stream>>>(w_gnode, b_gs, o_TX, w_Zin);
    // 6. Z GEMM split-K(4) + reduce
    gemm_zsplit<<<dim3(16, 4, 4), blk, 0, stream>>>(w_Zin, W_zx, w_zpart);
    zreduce<<<dim3((Bb * OUTF) / 256), blk, 0, stream>>>(w_zpart, b_zx, o_ZX);
}

// Round 19
// 389.669 us; speedup vs baseline: 1.1554x; 1.1554x over previous
//
#include <hip/hip_runtime.h>
#include <hip/hip_bf16.h>
#include <math.h>

// Dynamic_MHGCN_FusionLayer: B=256, N=131, IN=512, OUT=1024, H=4, D=256
// Round 19: exact revert to R17 (389us, best). R18's register diet regressed
// (occupancy gain < adj-re-read/2-pass traffic loss). R17 = nodeatt fused in
// gemm_node, direct-transposed GrawT, edge_agg with Wb-in-LDS + rolling
// B prefetch, split-K(4) Z GEMM.

#define LRELU(x) ((x) > 0.f ? (x) : 0.01f * (x))

constexpr int Bb = 256;
constexpr int Nn = 131;
constexpr int INF_ = 512;
constexpr int OUTF = 1024;
constexpr int Hh = 4;
constexpr int Dd = 256;
constexpr int OC2 = 2048;  // Gcat: Gk(0..1023) | Gq(1024..2047)
constexpr int YP = 168;    // GrawT row stride (shorts)
constexpr int WLP = 174;   // WbL LDS row stride (shorts): odd dwords -> conflict-free
constexpr int KAGG = 160;

typedef __attribute__((ext_vector_type(8))) short bf16x8;
typedef __attribute__((ext_vector_type(4))) float f32x4;

__device__ __forceinline__ float bf2f(short s) {
    union { float f; unsigned u; } c;
    c.u = ((unsigned)(unsigned short)s) << 16;
    return c.f;
}

__device__ __forceinline__ void gload_lds16(const void* g, void* lds) {
    __builtin_amdgcn_global_load_lds(
        (const __attribute__((address_space(1))) void*)g,
        (__attribute__((address_space(3))) void*)lds, 16, 0, 0);
}

// ---------------------------------------------------------------------------
// fp32 -> bf16 conversion. Wcat packed as [Wgk | Wgq | Wgx] (3072 x 512).
// ---------------------------------------------------------------------------
__global__ __launch_bounds__(256) void convert_kernel(
    const float* __restrict__ node, const float* __restrict__ Wgx,
    const float* __restrict__ Wgk, const float* __restrict__ Wgq,
    __hip_bfloat16* __restrict__ node_bf, __hip_bfloat16* __restrict__ Wcat)
{
    const size_t NE = (size_t)Bb * Nn * INF_ / 4;
    const size_t WE = (size_t)3072 * INF_ / 4;
    for (size_t i = (size_t)blockIdx.x * 256 + threadIdx.x; i < NE + WE;
         i += (size_t)gridDim.x * 256) {
        if (i < NE) {
            const float4 v = ((const float4*)node)[i];
            __hip_bfloat16* o = node_bf + i * 4;
            o[0] = __float2bfloat16(v.x); o[1] = __float2bfloat16(v.y);
            o[2] = __float2bfloat16(v.z); o[3] = __float2bfloat16(v.w);
        } else {
            const size_t j = i - NE;
            const size_t which = j / (1024 * INF_ / 4);
            const float* src = (which == 0) ? Wgk : (which == 1 ? Wgq : Wgx);
            const size_t srcj = j - which * (1024 * INF_ / 4);
            const float4 v = ((const float4*)src)[srcj];
            __hip_bfloat16* o = Wcat + j * 4;
            o[0] = __float2bfloat16(v.x); o[1] = __float2bfloat16(v.y);
            o[2] = __float2bfloat16(v.z); o[3] = __float2bfloat16(v.w);
        }
    }
}

// ---------------------------------------------------------------------------
// Fused node GEMM (bf16 MFMA): 128x128 tile, 4 waves (2x2), BK=64 single
// buffer, XOR granule swizzle (0 bank conflicts).
// o-tiles 0..7  (Gk):  row-major stores + node-att score partials -> spart.
// o-tiles 8..15 (Gq):  row-major stores.
// o-tiles 16..23 (Graw): lrelu(.+b_gx) transposed via LDS -> GrawT (coalesced).
// ---------------------------------------------------------------------------
__global__ __launch_bounds__(256, 4) void gemm_node_mfma(
    const __hip_bfloat16* __restrict__ A, const __hip_bfloat16* __restrict__ W,
    const float* __restrict__ bias_gx, const float* __restrict__ Tq,
    __hip_bfloat16* __restrict__ Gcat, __hip_bfloat16* __restrict__ GrawT,
    float* __restrict__ spart)
{
    __shared__ short SM[16384];          // As=[0,8192), Bs=[8192,16384)
    short* As = SM;
    short* Bs = SM + 8192;
    const int tid = threadIdx.x;
    const int wave = tid >> 6, lane = tid & 63;
    const int m0 = blockIdx.y * 128, o0 = blockIdx.x * 128;
    const int wr = wave >> 1, wc = wave & 1;

    f32x4 acc[4][4] = {};
    const short* Asrc = (const short*)A;
    const short* Wsrc = (const short*)W;
    const int gsrc = ((tid & 7) ^ ((tid >> 3) & 7)) * 8;
    const int srow = tid >> 3;

    for (int kt = 0; kt < 8; ++kt) {
        const int k0 = kt * 64;
        #pragma unroll
        for (int j = 0; j < 4; ++j) {
            const int row = j * 32 + srow;
            gload_lds16(Asrc + (size_t)(m0 + row) * INF_ + k0 + gsrc,
                        &As[(j * 256 + (tid & ~63)) * 8]);
            gload_lds16(Wsrc + (size_t)(o0 + row) * INF_ + k0 + gsrc,
                        &Bs[(j * 256 + (tid & ~63)) * 8]);
        }
        __syncthreads();
        #pragma unroll
        for (int ks = 0; ks < 2; ++ks) {
            const int sa = ((ks * 4 + (lane >> 4)) ^ (lane & 7)) * 8;
            bf16x8 af[4], bfr[4];
            #pragma unroll
            for (int i = 0; i < 4; ++i) {
                af[i]  = *(const bf16x8*)&As[(wr * 64 + i * 16 + (lane & 15)) * 64 + sa];
                bfr[i] = *(const bf16x8*)&Bs[(wc * 64 + i * 16 + (lane & 15)) * 64 + sa];
            }
            #pragma unroll
            for (int mi = 0; mi < 4; ++mi)
                #pragma unroll
                for (int ni = 0; ni < 4; ++ni)
                    acc[mi][ni] = __builtin_amdgcn_mfma_f32_16x16x32_bf16(
                        af[mi], bfr[ni], acc[mi][ni], 0, 0, 0);
        }
        __syncthreads();
    }

    const int cc = lane & 15;
    const int rg = (lane >> 4) * 4;
    if (o0 < 1024) {
        // Gk tile: stores + node-att score partials
        const int blo = m0 / 131;
        const int msw = (blo + 1) * 131;
        float tqA[4], tqB[4];
        #pragma unroll
        for (int ni = 0; ni < 4; ++ni) {
            const int o = o0 + wc * 64 + ni * 16 + cc;
            tqA[ni] = Tq[(size_t)blo * OUTF + o];
            tqB[ni] = (blo + 1 < Bb) ? Tq[(size_t)(blo + 1) * OUTF + o] : 0.f;
        }
        float sc[4][4] = {};
        #pragma unroll
        for (int mi = 0; mi < 4; ++mi)
            #pragma unroll
            for (int ni = 0; ni < 4; ++ni) {
                const int o = o0 + wc * 64 + ni * 16 + cc;
                #pragma unroll
                for (int r = 0; r < 4; ++r) {
                    const int m = m0 + wr * 64 + mi * 16 + rg + r;
                    float v = acc[mi][ni][r];
                    v = LRELU(v);
                    Gcat[(size_t)m * OC2 + o] = __float2bfloat16(v);
                    sc[mi][r] += v * ((m >= msw) ? tqB[ni] : tqA[ni]);
                }
            }
        const int slot = (o0 >> 6) + wc;
        #pragma unroll
        for (int mi = 0; mi < 4; ++mi)
            #pragma unroll
            for (int r = 0; r < 4; ++r) {
                float s = sc[mi][r];
                s += __shfl_xor(s, 1); s += __shfl_xor(s, 2);
                s += __shfl_xor(s, 4); s += __shfl_xor(s, 8);
                if (cc == 0) {
                    const int m = m0 + wr * 64 + mi * 16 + rg + r;
                    spart[(size_t)m * 16 + slot] = s;
                }
            }
    } else if (o0 < OC2) {
        // Gq tile: plain row-major stores
        #pragma unroll
        for (int mi = 0; mi < 4; ++mi)
            #pragma unroll
            for (int ni = 0; ni < 4; ++ni) {
                const int o = o0 + wc * 64 + ni * 16 + cc;
                #pragma unroll
                for (int r = 0; r < 4; ++r) {
                    const int m = m0 + wr * 64 + mi * 16 + rg + r;
                    float v = acc[mi][ni][r];
                    v = LRELU(v);
                    Gcat[(size_t)m * OC2 + o] = __float2bfloat16(v);
                }
            }
    } else {
        // Graw tile: lrelu(.+b_gx); transposed via LDS, coalesced 16B stores
        const int og0 = o0 - OC2;
        const int h = og0 >> 8;
        const int dbase = og0 & 255;
        __syncthreads();
        #pragma unroll
        for (int mi = 0; mi < 4; ++mi)
            #pragma unroll
            for (int ni = 0; ni < 4; ++ni) {
                const int dloc = wc * 64 + ni * 16 + cc;
                const float badd = bias_gx[og0 + dloc];
                #pragma unroll
                for (int r = 0; r < 4; ++r) {
                    const int row = wr * 64 + mi * 16 + rg + r;
                    float v = acc[mi][ni][r] + badd;
                    v = LRELU(v);
                    __hip_bfloat16 hb = __float2bfloat16(v);
                    const int g = row >> 3;
                    SM[dloc * 128 + ((g ^ (dloc & 7)) << 3) + (row & 7)] = *(short*)&hb;
                }
            }
        __syncthreads();
        short* GT = (short*)GrawT;
        #pragma unroll
        for (int j = 0; j < 8; ++j) {
            const int task = j * 256 + tid;
            const int dloc = task >> 4;
            const int g = task & 15;
            const bf16x8 v = *(const bf16x8*)&SM[dloc * 128 + ((g ^ (dloc & 7)) << 3)];
            const int m = m0 + g * 8;
            const int gd = dbase + dloc;
            const int b0 = m / 131;
            const int n0 = m - b0 * 131;
            if (n0 + 8 <= Nn) {
                *(bf16x8*)&GT[((size_t)(b0 * Hh + h) * 256 + gd) * YP + n0] = v;
            } else {
                #pragma unroll
                for (int e = 0; e < 8; ++e) {
                    const int mm = m + e;
                    const int bb = mm / 131;
                    const int nn = mm - bb * 131;
                    GT[((size_t)(bb * Hh + h) * 256 + gd) * YP + nn] = ((const short*)&v)[e];
                }
            }
        }
    }
}

// ---------------------------------------------------------------------------
// Merged tabular GEMMs (fp32): which=0 -> T_X (bias b_tx), which=1 -> T_q.
// ---------------------------------------------------------------------------
__global__ __launch_bounds__(256) void gemm_tab(
    const float* __restrict__ Atab, const float* __restrict__ Wtx,
    const float* __restrict__ btx, const float* __restrict__ Wtq,
    float* __restrict__ Ctx, float* __restrict__ Ctq)
{
    const int which = blockIdx.x >> 4;
    const float* Wm = which ? Wtq : Wtx;
    float* C = which ? Ctq : Ctx;
    __shared__ float As[16][68];
    __shared__ float Ws[16][68];
    const int tid = threadIdx.x;
    const int tx = tid & 15;
    const int ty = tid >> 4;
    const int m0 = blockIdx.y * 64;
    const int o0 = (blockIdx.x & 15) * 64;

    float acc[4][4] = {};
    for (int k0 = 0; k0 < INF_; k0 += 16) {
        const int j = tid & 15;
        const int i = tid >> 4;
        #pragma unroll
        for (int r = 0; r < 4; ++r)
            As[j][i + 16 * r] = Atab[(size_t)(m0 + i + 16 * r) * INF_ + k0 + j];
        #pragma unroll
        for (int r = 0; r < 4; ++r)
            Ws[j][i + 16 * r] = Wm[(size_t)(o0 + i + 16 * r) * INF_ + k0 + j];
        __syncthreads();
        #pragma unroll
        for (int kk = 0; kk < 16; ++kk) {
            const float4 av = *(const float4*)&As[kk][ty * 4];
            const float4 wv = *(const float4*)&Ws[kk][tx * 4];
            const float a[4] = {av.x, av.y, av.z, av.w};
            const float w[4] = {wv.x, wv.y, wv.z, wv.w};
            #pragma unroll
            for (int r = 0; r < 4; ++r)
                #pragma unroll
                for (int c = 0; c < 4; ++c)
                    acc[r][c] += a[r] * w[c];
        }
        __syncthreads();
    }
    #pragma unroll
    for (int r = 0; r < 4; ++r) {
        const int m = m0 + ty * 4 + r;
        const int o = o0 + tx * 4;
        float4 v;
        float* vp = (float*)&v;
        #pragma unroll
        for (int c = 0; c < 4; ++c) {
            float t = acc[r][c] + (which ? 0.f : btx[o + c]);
            vp[c] = LRELU(t);
        }
        *(float4*)&C[(size_t)m * OUTF + o] = v;
    }
}

// ---------------------------------------------------------------------------
// Zin build: Zin[b][0:1024] = lrelu(gnode + bgs), Zin[b][1024:2048] = T_X.
// ---------------------------------------------------------------------------
__global__ __launch_bounds__(256) void zin_build(
    const float* __restrict__ gnode, const float* __restrict__ bgs,
    const float* __restrict__ Tx, float* __restrict__ Zin)
{
    const int idx = blockIdx.x * 256 + threadIdx.x;
    const int b = idx >> 10, o = idx & 1023;
    const float s = gnode[idx] + bgs[0];
    Zin[(size_t)b * 2048 + o] = LRELU(s);
    Zin[(size_t)b * 2048 + 1024 + o] = Tx[idx];
}

// ---------------------------------------------------------------------------
// Z GEMM split-K: grid (16,4,4); chunk kz covers K in [kz*512,(kz+1)*512).
// ---------------------------------------------------------------------------
__global__ __launch_bounds__(256) void gemm_zsplit(
    const float* __restrict__ A, const float* __restrict__ W,
    float* __restrict__ P)
{
    __shared__ float As[16][68];
    __shared__ float Ws[16][68];
    const int tid = threadIdx.x;
    const int tx = tid & 15;
    const int ty = tid >> 4;
    const int m0 = blockIdx.y * 64;
    const int o0 = blockIdx.x * 64;
    const int kbase = blockIdx.z * 512;

    float acc[4][4] = {};
    for (int k0 = kbase; k0 < kbase + 512; k0 += 16) {
        const int j = tid & 15;
        const int i = tid >> 4;
        #pragma unroll
        for (int r = 0; r < 4; ++r)
            As[j][i + 16 * r] = A[(size_t)(m0 + i + 16 * r) * 2048 + k0 + j];
        #pragma unroll
        for (int r = 0; r < 4; ++r)
            Ws[j][i + 16 * r] = W[(size_t)(o0 + i + 16 * r) * 2048 + k0 + j];
        __syncthreads();
        #pragma unroll
        for (int kk = 0; kk < 16; ++kk) {
            const float4 av = *(const float4*)&As[kk][ty * 4];
            const float4 wv = *(const float4*)&Ws[kk][tx * 4];
            const float a[4] = {av.x, av.y, av.z, av.w};
            const float w[4] = {wv.x, wv.y, wv.z, wv.w};
            #pragma unroll
            for (int r = 0; r < 4; ++r)
                #pragma unroll
                for (int c = 0; c < 4; ++c)
                    acc[r][c] += a[r] * w[c];
        }
        __syncthreads();
    }
    float* pz = P + (size_t)blockIdx.z * Bb * OUTF;
    #pragma unroll
    for (int r = 0; r < 4; ++r) {
        const int m = m0 + ty * 4 + r;
        const int o = o0 + tx * 4;
        float4 v;
        float* vp = (float*)&v;
        #pragma unroll
        for (int c = 0; c < 4; ++c) vp[c] = acc[r][c];
        *(float4*)&pz[(size_t)m * OUTF + o] = v;
    }
}

// ---------------------------------------------------------------------------
// Z reduce: C = lrelu(sum_4 P + bzx).
// ---------------------------------------------------------------------------
__global__ __launch_bounds__(256) void zreduce(
    const float* __restrict__ P, const float* __restrict__ bzx,
    float* __restrict__ C)
{
    const int idx = blockIdx.x * 256 + threadIdx.x;
    const int o = idx & 1023;
    const size_t STRIDE = (size_t)Bb * OUTF;
    float s = P[idx] + P[STRIDE + idx] + P[2 * STRIDE + idx] + P[3 * STRIDE + idx]
            + bzx[o];
    C[idx] = LRELU(s);
}

// ---------------------------------------------------------------------------
// nodeatt_soft: s[b,n] = (1/32) * sum_16 spart[(b*131+n)][slot]; softmax; +1.
// ---------------------------------------------------------------------------
__global__ __launch_bounds__(256) void nodeatt_soft(
    const float* __restrict__ spart, float* __restrict__ att)
{
    const int b = blockIdx.x;
    __shared__ float sc[136];
    const int tid = threadIdx.x;
    if (tid < Nn) {
        const float* sp = spart + (size_t)(b * Nn + tid) * 16;
        float s = 0.f;
        #pragma unroll
        for (int i = 0; i < 16; ++i) s += sp[i];
        sc[tid] = s * (1.f / 32.f);
    }
    __syncthreads();
    if (tid < 64) {
        const float v1 = sc[tid];
        const float v2 = sc[tid + 64];
        const float v3 = (tid < 3) ? sc[tid + 128] : -1e30f;
        float m = fmaxf(fmaxf(v1, v2), v3);
        #pragma unroll
        for (int off = 32; off; off >>= 1) m = fmaxf(m, __shfl_xor(m, off));
        const float e1 = expf(v1 - m);
        const float e2 = expf(v2 - m);
        const float e3 = (tid < 3) ? expf(v3 - m) : 0.f;
        float s = e1 + e2 + e3;
        #pragma unroll
        for (int off = 32; off; off >>= 1) s += __shfl_xor(s, off);
        const float inv = 1.f / s;
        float* ab = att + (size_t)b * Nn;
        ab[tid] = e1 * inv + 1.f;
        ab[tid + 64] = e2 * inv + 1.f;
        if (tid < 3) ab[tid + 128] = e3 * inv + 1.f;
    }
}

// ---------------------------------------------------------------------------
// edge_agg (R17 structure): one block (9 waves) per (b,h).
// ---------------------------------------------------------------------------
__global__ __launch_bounds__(576) void edge_agg(
    const __hip_bfloat16* __restrict__ Gcat, const float* __restrict__ adj,
    const float* __restrict__ att, const __hip_bfloat16* __restrict__ GrawT,
    const float* __restrict__ Wgs, float* __restrict__ edge,
    float* __restrict__ Gout, float* __restrict__ gnode)
{
    __shared__ short SM[25056];
    __shared__ float rsL[144 * 3];
    __shared__ float dxL[Nn], daL[Nn], attL[Nn], wgsL[Nn];

    const int bh = blockIdx.x, b = bh >> 2, h = bh & 3;
    const int tid = threadIdx.x;
    const int lane = tid & 63, wid = tid >> 6;
    const int wr = wid / 3, wc = wid % 3;
    if (tid < Nn) { attL[tid] = att[(size_t)b * Nn + tid]; wgsL[tid] = Wgs[tid]; }

    const short* qb = (const short*)Gcat + (size_t)b * Nn * OC2 + 1024 + h * Dd;
    const short* kb = (const short*)Gcat + (size_t)b * Nn * OC2 + h * Dd;
    const short* gsrcT = (const short*)GrawT + (size_t)bh * 256 * YP;

    int srow = tid >> 2; if (srow > Nn - 1) srow = Nn - 1;
    const int gsrc = ((tid & 3) ^ ((tid >> 3) & 3)) * 8;
    const int dstoff = (tid & ~63) * 8;

    auto STAGE = [&](int buf, int k0) {
        gload_lds16(qb + (size_t)srow * OC2 + k0 + gsrc, &SM[buf * 4608 + dstoff]);
        gload_lds16(kb + (size_t)srow * OC2 + k0 + gsrc, &SM[9216 + buf * 4608 + dstoff]);
    };

    f32x4 acc[3][3] = {};
    const int sa = ((lane >> 4) ^ ((lane >> 1) & 3)) * 8;

    STAGE(0, 0);
    for (int t = 0; t < 8; ++t) {
        const int buf = t & 1;
        if (t < 7) {
            STAGE(buf ^ 1, (t + 1) * 32);
            asm volatile("s_waitcnt vmcnt(2)" ::: "memory");
        } else {
            asm volatile("s_waitcnt vmcnt(0)" ::: "memory");
        }
        __builtin_amdgcn_s_barrier();
        __builtin_amdgcn_sched_barrier(0);
        bf16x8 qf[3], kf[3];
        #pragma unroll
        for (int i = 0; i < 3; ++i) {
            qf[i] = *(const bf16x8*)&SM[buf * 4608 + (wr * 48 + i * 16 + (lane & 15)) * 32 + sa];
            kf[i] = *(const bf16x8*)&SM[9216 + buf * 4608 + (wc * 48 + i * 16 + (lane & 15)) * 32 + sa];
        }
        __builtin_amdgcn_s_setprio(1);
        #pragma unroll
        for (int mi = 0; mi < 3; ++mi)
            #pragma unroll
            for (int ni = 0; ni < 3; ++ni)
                acc[mi][ni] = __builtin_amdgcn_mfma_f32_16x16x32_bf16(
                    qf[mi], kf[ni], acc[mi][ni], 0, 0, 0);
        __builtin_amdgcn_s_setprio(0);
        __builtin_amdgcn_sched_barrier(0);
        if (t < 7) __builtin_amdgcn_s_barrier();
    }

    // phase 2: adj -> regs, sigmoid, edge write, slotted rowsums
    const float* adjb = adj + (size_t)b * Nn * Nn;
    float* edgeb = edge + (size_t)bh * Nn * Nn;
    const int cc = lane & 15;
    const int rg = (lane >> 4) * 4;
    float areg[3][3][4];
    #pragma unroll
    for (int mi = 0; mi < 3; ++mi) {
        float rsum[4] = {0.f, 0.f, 0.f, 0.f};
        #pragma unroll
        for (int ni = 0; ni < 3; ++ni) {
            const int y = wc * 48 + ni * 16 + cc;
            #pragma unroll
            for (int r = 0; r < 4; ++r) {
                const int x = wr * 48 + mi * 16 + rg + r;
                const bool in = (x < Nn) && (y < Nn);
                const float a = in ? adjb[x * Nn + y] : 0.f;
                areg[mi][ni][r] = a;
                const float e = 1.f / (1.f + __expf(-acc[mi][ni][r] * (1.f / 16.f)));
                acc[mi][ni][r] = e;
                if (in) {
                    edgeb[x * Nn + y] = e;
                    rsum[r] += a * e;
                }
            }
        }
        #pragma unroll
        for (int r = 0; r < 4; ++r) {
            float v = rsum[r];
            v += __shfl_xor(v, 1); v += __shfl_xor(v, 2);
            v += __shfl_xor(v, 4); v += __shfl_xor(v, 8);
            const int x = wr * 48 + mi * 16 + rg + r;
            if (cc == 0 && x < Nn) rsL[x * 3 + wc] = v;
        }
    }
    __syncthreads();
    if (tid < Nn) {
        const float s = rsL[tid * 3] + rsL[tid * 3 + 1] + rsL[tid * 3 + 2];
        const float dv = rsqrtf(s + 1.f);
        dxL[tid] = dv;
        daL[tid] = dv * attL[tid];
    }
    __syncthreads();   // Qs/Ks dead -> SM reusable as WbL

    // phase 2b: prefetch chunk-0 B-fragments (L2-resident GrawT)
    const int brow0 = wid * 32 + (lane & 15);
    const int bcol = (lane >> 4) * 8;
    bf16x8 bcur0, bcur1;
    if (wid < 8) {
        bcur0 = *(const bf16x8*)&gsrcT[(size_t)brow0 * YP + 0 + bcol];
        bcur1 = *(const bf16x8*)&gsrcT[(size_t)(brow0 + 16) * YP + 0 + bcol];
    }

    // phase 3: Wb -> LDS (stride WLP). Zero y in [131,160).
    short* WbL = SM;
    for (int i = tid; i < 144 * 29; i += 576) {
        const int x = i / 29, y = 131 + i % 29;
        WbL[x * WLP + y] = 0;
    }
    #pragma unroll
    for (int mi = 0; mi < 3; ++mi)
        #pragma unroll
        for (int ni = 0; ni < 3; ++ni) {
            const int y = wc * 48 + ni * 16 + cc;
            #pragma unroll
            for (int r = 0; r < 4; ++r) {
                const int x = wr * 48 + mi * 16 + rg + r;
                if (x < Nn && y < Nn) {
                    float a = areg[mi][ni][r] * acc[mi][ni][r];
                    if (x == y) a += 1.f;
                    const float w = dxL[x] * a * daL[y];
                    __hip_bfloat16 hb = __float2bfloat16(w);
                    WbL[(size_t)x * WLP + y] = *(short*)&hb;
                }
            }
        }
    __syncthreads();

    // phase 4: aggregation MFMA — af from WbL, bfr rolling register prefetch.
    if (wid < 8) {
        f32x4 gacc[9][2] = {};
        #pragma unroll
        for (int kc = 0; kc < 5; ++kc) {
            bf16x8 bnxt0, bnxt1;
            if (kc < 4) {
                bnxt0 = *(const bf16x8*)&gsrcT[(size_t)brow0 * YP + (kc + 1) * 32 + bcol];
                bnxt1 = *(const bf16x8*)&gsrcT[(size_t)(brow0 + 16) * YP + (kc + 1) * 32 + bcol];
            }
            bf16x8 af[9];
            #pragma unroll
            for (int mi = 0; mi < 9; ++mi)
                af[mi] = *(const bf16x8*)&WbL[(mi * 16 + (lane & 15)) * WLP + kc * 32 + (lane >> 4) * 8];
            __builtin_amdgcn_s_setprio(1);
            #pragma unroll
            for (int mi = 0; mi < 9; ++mi) {
                gacc[mi][0] = __builtin_amdgcn_mfma_f32_16x16x32_bf16(
                    af[mi], bcur0, gacc[mi][0], 0, 0, 0);
                gacc[mi][1] = __builtin_amdgcn_mfma_f32_16x16x32_bf16(
                    af[mi], bcur1, gacc[mi][1], 0, 0, 0);
            }
            __builtin_amdgcn_s_setprio(0);
            if (kc < 4) { bcur0 = bnxt0; bcur1 = bnxt1; }
        }

        // phase 5: Gout + gnode colsum (8 waves)
        float* gob = Gout + (size_t)b * Nn * OUTF + h * Dd;
        float gp[2] = {0.f, 0.f};
        #pragma unroll
        for (int mi = 0; mi < 9; ++mi)
            #pragma unroll
            for (int ni = 0; ni < 2; ++ni) {
                const int d = wid * 32 + ni * 16 + (lane & 15);
                #pragma unroll
                for (int r = 0; r < 4; ++r) {
                    const int x = mi * 16 + (lane >> 4) * 4 + r;
                    if (x < Nn) {
                        gob[(size_t)x * OUTF + d] = gacc[mi][ni][r];
                        gp[ni] += wgsL[x] * gacc[mi][ni][r];
                    }
                }
            }
        #pragma unroll
        for (int ni = 0; ni < 2; ++ni) {
            gp[ni] += __shfl_xor(gp[ni], 16);
            gp[ni] += __shfl_xor(gp[ni], 32);
            if (lane < 16)
                gnode[(size_t)b * OUTF + h * Dd + wid * 32 + ni * 16 + lane] = gp[ni];
        }
    }
}

// ---------------------------------------------------------------------------
extern "C" void kernel_launch(void* const* d_in, const int* in_sizes, int n_in,
                              void* d_out, int out_size, void* d_ws, size_t ws_size,
                              hipStream_t stream) {
    const float* tab  = (const float*)d_in[0];
    const float* node = (const float*)d_in[1];
    const float* adj  = (const float*)d_in[2];
    const float* W_gx = (const float*)d_in[3];
    const float* b_gx = (const float*)d_in[4];
    const float* W_tx = (const float*)d_in[5];
    const float* b_tx = (const float*)d_in[6];
    const float* W_gk = (const float*)d_in[7];
    const float* W_tq = (const float*)d_in[8];
    const float* W_gq = (const float*)d_in[9];
    const float* W_gs = (const float*)d_in[10];
    const float* b_gs = (const float*)d_in[11];
    const float* W_zx = (const float*)d_in[12];
    const float* b_zx = (const float*)d_in[13];

    const size_t GX_ELEMS = (size_t)Bb * Nn * OUTF;   // 34,340,864
    const int M_NODE = Bb * Nn;                       // 33536

    float* out   = (float*)d_out;
    float* o_GX  = out;
    float* o_TX  = o_GX + GX_ELEMS;
    float* o_ZX  = o_TX + (size_t)Bb * OUTF;
    float* o_ATT = o_ZX + (size_t)Bb * OUTF;
    float* o_EDG = o_ATT + (size_t)Bb * Nn;

    // workspace: bf16 regions first, then fp32
    __hip_bfloat16* wb      = (__hip_bfloat16*)d_ws;
    __hip_bfloat16* w_nodeb = wb;                                          // 33536*512
    __hip_bfloat16* w_Wcat  = w_nodeb + (size_t)M_NODE * INF_;             // 3072*512
    __hip_bfloat16* w_Gcat  = w_Wcat + (size_t)3072 * INF_;                // 33536*2048
    __hip_bfloat16* w_GrawT = w_Gcat + (size_t)M_NODE * OC2;               // 1024*256*168
    float* wf       = (float*)(w_GrawT + (size_t)Bb * Hh * 256 * YP);
    float* w_Tq     = wf;
    float* w_Zin    = w_Tq + (size_t)Bb * OUTF;                            // 256*2048
    float* w_gnode  = w_Zin + (size_t)Bb * 2 * OUTF;                       // 256*1024
    float* w_spart  = w_gnode + (size_t)Bb * OUTF;                         // 33536*16
    float* w_zpart  = w_spart + (size_t)M_NODE * 16;                       // 4*256*1024

    const dim3 blk(256);

    // 0. fp32 -> bf16 (Wcat = [Wgk | Wgq | Wgx])
    convert_kernel<<<dim3(2048), blk, 0, stream>>>(node, W_gx, W_gk, W_gq,
                                                   w_nodeb, w_Wcat);
    // 1. merged tabular GEMMs (T_X + T_q)
    gemm_tab<<<dim3(32, 4), blk, 0, stream>>>(tab, W_tx, b_tx, W_tq, o_TX, w_Tq);
    // 2. fused node GEMM -> Gcat + GrawT + node-att score partials
    gemm_node_mfma<<<dim3(24, M_NODE / 128), blk, 0, stream>>>(
        w_nodeb, w_Wcat, b_gx, w_Tq, w_Gcat, w_GrawT, w_spart);
    // 3. node attention softmax (from partials) -> o_ATT
    nodeatt_soft<<<dim3(Bb), blk, 0, stream>>>(w_spart, o_ATT);
    // 4. fused edge attention + rowsum + dinv + Wb(LDS) + aggregation + gn
    edge_agg<<<dim3(Bb * Hh), dim3(576), 0, stream>>>(
        w_Gcat, adj, o_ATT, w_GrawT, W_gs, o_EDG, o_GX, w_gnode);
    // 5. Zin build
    zin_build<<<dim3((Bb * OUTF) / 256), blk, 0, stream>>>(w_gnode, b_gs, o_TX, w_Zin);
    // 6. Z GEMM split-K(4) + reduce
    gemm_zsplit<<<dim3(16, 4, 4), blk, 0, stream>>>(w_Zin, W_zx, w_zpart);
    zreduce<<<dim3((Bb * OUTF) / 256), blk, 0, stream>>>(w_zpart, b_zx, o_ZX);
}

// Round 20
// 364.792 us; speedup vs baseline: 1.2342x; 1.0682x over previous
//
#include <hip/hip_runtime.h>
#include <hip/hip_bf16.h>
#include <math.h>

// Dynamic_MHGCN_FusionLayer: B=256, N=131, IN=512, OUT=1024, H=4, D=256
// Round 20: R17 + issue-early loads in edge_agg (T14): adj->areg issued
// BEFORE the QK^T loop (latency folds into iter-0 vmcnt wait); GrawT chunk-0
// register prefetch moved directly after QK^T (hidden under phase 2/3 VALU).
// No semantic change; peak register pressure unchanged (phase 4 dominates).

#define LRELU(x) ((x) > 0.f ? (x) : 0.01f * (x))

constexpr int Bb = 256;
constexpr int Nn = 131;
constexpr int INF_ = 512;
constexpr int OUTF = 1024;
constexpr int Hh = 4;
constexpr int Dd = 256;
constexpr int OC2 = 2048;  // Gcat: Gk(0..1023) | Gq(1024..2047)
constexpr int YP = 168;    // GrawT row stride (shorts)
constexpr int WLP = 174;   // WbL LDS row stride (shorts): odd dwords -> conflict-free
constexpr int KAGG = 160;

typedef __attribute__((ext_vector_type(8))) short bf16x8;
typedef __attribute__((ext_vector_type(4))) float f32x4;

__device__ __forceinline__ float bf2f(short s) {
    union { float f; unsigned u; } c;
    c.u = ((unsigned)(unsigned short)s) << 16;
    return c.f;
}

__device__ __forceinline__ void gload_lds16(const void* g, void* lds) {
    __builtin_amdgcn_global_load_lds(
        (const __attribute__((address_space(1))) void*)g,
        (__attribute__((address_space(3))) void*)lds, 16, 0, 0);
}

// ---------------------------------------------------------------------------
// fp32 -> bf16 conversion. Wcat packed as [Wgk | Wgq | Wgx] (3072 x 512).
// ---------------------------------------------------------------------------
__global__ __launch_bounds__(256) void convert_kernel(
    const float* __restrict__ node, const float* __restrict__ Wgx,
    const float* __restrict__ Wgk, const float* __restrict__ Wgq,
    __hip_bfloat16* __restrict__ node_bf, __hip_bfloat16* __restrict__ Wcat)
{
    const size_t NE = (size_t)Bb * Nn * INF_ / 4;
    const size_t WE = (size_t)3072 * INF_ / 4;
    for (size_t i = (size_t)blockIdx.x * 256 + threadIdx.x; i < NE + WE;
         i += (size_t)gridDim.x * 256) {
        if (i < NE) {
            const float4 v = ((const float4*)node)[i];
            __hip_bfloat16* o = node_bf + i * 4;
            o[0] = __float2bfloat16(v.x); o[1] = __float2bfloat16(v.y);
            o[2] = __float2bfloat16(v.z); o[3] = __float2bfloat16(v.w);
        } else {
            const size_t j = i - NE;
            const size_t which = j / (1024 * INF_ / 4);
            const float* src = (which == 0) ? Wgk : (which == 1 ? Wgq : Wgx);
            const size_t srcj = j - which * (1024 * INF_ / 4);
            const float4 v = ((const float4*)src)[srcj];
            __hip_bfloat16* o = Wcat + j * 4;
            o[0] = __float2bfloat16(v.x); o[1] = __float2bfloat16(v.y);
            o[2] = __float2bfloat16(v.z); o[3] = __float2bfloat16(v.w);
        }
    }
}

// ---------------------------------------------------------------------------
// Fused node GEMM (bf16 MFMA): 128x128 tile, 4 waves (2x2), BK=64 single
// buffer, XOR granule swizzle (0 bank conflicts).
// o-tiles 0..7  (Gk):  row-major stores + node-att score partials -> spart.
// o-tiles 8..15 (Gq):  row-major stores.
// o-tiles 16..23 (Graw): lrelu(.+b_gx) transposed via LDS -> GrawT (coalesced).
// ---------------------------------------------------------------------------
__global__ __launch_bounds__(256, 4) void gemm_node_mfma(
    const __hip_bfloat16* __restrict__ A, const __hip_bfloat16* __restrict__ W,
    const float* __restrict__ bias_gx, const float* __restrict__ Tq,
    __hip_bfloat16* __restrict__ Gcat, __hip_bfloat16* __restrict__ GrawT,
    float* __restrict__ spart)
{
    __shared__ short SM[16384];          // As=[0,8192), Bs=[8192,16384)
    short* As = SM;
    short* Bs = SM + 8192;
    const int tid = threadIdx.x;
    const int wave = tid >> 6, lane = tid & 63;
    const int m0 = blockIdx.y * 128, o0 = blockIdx.x * 128;
    const int wr = wave >> 1, wc = wave & 1;

    f32x4 acc[4][4] = {};
    const short* Asrc = (const short*)A;
    const short* Wsrc = (const short*)W;
    const int gsrc = ((tid & 7) ^ ((tid >> 3) & 7)) * 8;
    const int srow = tid >> 3;

    for (int kt = 0; kt < 8; ++kt) {
        const int k0 = kt * 64;
        #pragma unroll
        for (int j = 0; j < 4; ++j) {
            const int row = j * 32 + srow;
            gload_lds16(Asrc + (size_t)(m0 + row) * INF_ + k0 + gsrc,
                        &As[(j * 256 + (tid & ~63)) * 8]);
            gload_lds16(Wsrc + (size_t)(o0 + row) * INF_ + k0 + gsrc,
                        &Bs[(j * 256 + (tid & ~63)) * 8]);
        }
        __syncthreads();
        #pragma unroll
        for (int ks = 0; ks < 2; ++ks) {
            const int sa = ((ks * 4 + (lane >> 4)) ^ (lane & 7)) * 8;
            bf16x8 af[4], bfr[4];
            #pragma unroll
            for (int i = 0; i < 4; ++i) {
                af[i]  = *(const bf16x8*)&As[(wr * 64 + i * 16 + (lane & 15)) * 64 + sa];
                bfr[i] = *(const bf16x8*)&Bs[(wc * 64 + i * 16 + (lane & 15)) * 64 + sa];
            }
            #pragma unroll
            for (int mi = 0; mi < 4; ++mi)
                #pragma unroll
                for (int ni = 0; ni < 4; ++ni)
                    acc[mi][ni] = __builtin_amdgcn_mfma_f32_16x16x32_bf16(
                        af[mi], bfr[ni], acc[mi][ni], 0, 0, 0);
        }
        __syncthreads();
    }

    const int cc = lane & 15;
    const int rg = (lane >> 4) * 4;
    if (o0 < 1024) {
        // Gk tile: stores + node-att score partials
        const int blo = m0 / 131;
        const int msw = (blo + 1) * 131;
        float tqA[4], tqB[4];
        #pragma unroll
        for (int ni = 0; ni < 4; ++ni) {
            const int o = o0 + wc * 64 + ni * 16 + cc;
            tqA[ni] = Tq[(size_t)blo * OUTF + o];
            tqB[ni] = (blo + 1 < Bb) ? Tq[(size_t)(blo + 1) * OUTF + o] : 0.f;
        }
        float sc[4][4] = {};
        #pragma unroll
        for (int mi = 0; mi < 4; ++mi)
            #pragma unroll
            for (int ni = 0; ni < 4; ++ni) {
                const int o = o0 + wc * 64 + ni * 16 + cc;
                #pragma unroll
                for (int r = 0; r < 4; ++r) {
                    const int m = m0 + wr * 64 + mi * 16 + rg + r;
                    float v = acc[mi][ni][r];
                    v = LRELU(v);
                    Gcat[(size_t)m * OC2 + o] = __float2bfloat16(v);
                    sc[mi][r] += v * ((m >= msw) ? tqB[ni] : tqA[ni]);
                }
            }
        const int slot = (o0 >> 6) + wc;
        #pragma unroll
        for (int mi = 0; mi < 4; ++mi)
            #pragma unroll
            for (int r = 0; r < 4; ++r) {
                float s = sc[mi][r];
                s += __shfl_xor(s, 1); s += __shfl_xor(s, 2);
                s += __shfl_xor(s, 4); s += __shfl_xor(s, 8);
                if (cc == 0) {
                    const int m = m0 + wr * 64 + mi * 16 + rg + r;
                    spart[(size_t)m * 16 + slot] = s;
                }
            }
    } else if (o0 < OC2) {
        // Gq tile: plain row-major stores
        #pragma unroll
        for (int mi = 0; mi < 4; ++mi)
            #pragma unroll
            for (int ni = 0; ni < 4; ++ni) {
                const int o = o0 + wc * 64 + ni * 16 + cc;
                #pragma unroll
                for (int r = 0; r < 4; ++r) {
                    const int m = m0 + wr * 64 + mi * 16 + rg + r;
                    float v = acc[mi][ni][r];
                    v = LRELU(v);
                    Gcat[(size_t)m * OC2 + o] = __float2bfloat16(v);
                }
            }
    } else {
        // Graw tile: lrelu(.+b_gx); transposed via LDS, coalesced 16B stores
        const int og0 = o0 - OC2;
        const int h = og0 >> 8;
        const int dbase = og0 & 255;
        __syncthreads();
        #pragma unroll
        for (int mi = 0; mi < 4; ++mi)
            #pragma unroll
            for (int ni = 0; ni < 4; ++ni) {
                const int dloc = wc * 64 + ni * 16 + cc;
                const float badd = bias_gx[og0 + dloc];
                #pragma unroll
                for (int r = 0; r < 4; ++r) {
                    const int row = wr * 64 + mi * 16 + rg + r;
                    float v = acc[mi][ni][r] + badd;
                    v = LRELU(v);
                    __hip_bfloat16 hb = __float2bfloat16(v);
                    const int g = row >> 3;
                    SM[dloc * 128 + ((g ^ (dloc & 7)) << 3) + (row & 7)] = *(short*)&hb;
                }
            }
        __syncthreads();
        short* GT = (short*)GrawT;
        #pragma unroll
        for (int j = 0; j < 8; ++j) {
            const int task = j * 256 + tid;
            const int dloc = task >> 4;
            const int g = task & 15;
            const bf16x8 v = *(const bf16x8*)&SM[dloc * 128 + ((g ^ (dloc & 7)) << 3)];
            const int m = m0 + g * 8;
            const int gd = dbase + dloc;
            const int b0 = m / 131;
            const int n0 = m - b0 * 131;
            if (n0 + 8 <= Nn) {
                *(bf16x8*)&GT[((size_t)(b0 * Hh + h) * 256 + gd) * YP + n0] = v;
            } else {
                #pragma unroll
                for (int e = 0; e < 8; ++e) {
                    const int mm = m + e;
                    const int bb = mm / 131;
                    const int nn = mm - bb * 131;
                    GT[((size_t)(bb * Hh + h) * 256 + gd) * YP + nn] = ((const short*)&v)[e];
                }
            }
        }
    }
}

// ---------------------------------------------------------------------------
// Merged tabular GEMMs (fp32): which=0 -> T_X (bias b_tx), which=1 -> T_q.
// ---------------------------------------------------------------------------
__global__ __launch_bounds__(256) void gemm_tab(
    const float* __restrict__ Atab, const float* __restrict__ Wtx,
    const float* __restrict__ btx, const float* __restrict__ Wtq,
    float* __restrict__ Ctx, float* __restrict__ Ctq)
{
    const int which = blockIdx.x >> 4;
    const float* Wm = which ? Wtq : Wtx;
    float* C = which ? Ctq : Ctx;
    __shared__ float As[16][68];
    __shared__ float Ws[16][68];
    const int tid = threadIdx.x;
    const int tx = tid & 15;
    const int ty = tid >> 4;
    const int m0 = blockIdx.y * 64;
    const int o0 = (blockIdx.x & 15) * 64;

    float acc[4][4] = {};
    for (int k0 = 0; k0 < INF_; k0 += 16) {
        const int j = tid & 15;
        const int i = tid >> 4;
        #pragma unroll
        for (int r = 0; r < 4; ++r)
            As[j][i + 16 * r] = Atab[(size_t)(m0 + i + 16 * r) * INF_ + k0 + j];
        #pragma unroll
        for (int r = 0; r < 4; ++r)
            Ws[j][i + 16 * r] = Wm[(size_t)(o0 + i + 16 * r) * INF_ + k0 + j];
        __syncthreads();
        #pragma unroll
        for (int kk = 0; kk < 16; ++kk) {
            const float4 av = *(const float4*)&As[kk][ty * 4];
            const float4 wv = *(const float4*)&Ws[kk][tx * 4];
            const float a[4] = {av.x, av.y, av.z, av.w};
            const float w[4] = {wv.x, wv.y, wv.z, wv.w};
            #pragma unroll
            for (int r = 0; r < 4; ++r)
                #pragma unroll
                for (int c = 0; c < 4; ++c)
                    acc[r][c] += a[r] * w[c];
        }
        __syncthreads();
    }
    #pragma unroll
    for (int r = 0; r < 4; ++r) {
        const int m = m0 + ty * 4 + r;
        const int o = o0 + tx * 4;
        float4 v;
        float* vp = (float*)&v;
        #pragma unroll
        for (int c = 0; c < 4; ++c) {
            float t = acc[r][c] + (which ? 0.f : btx[o + c]);
            vp[c] = LRELU(t);
        }
        *(float4*)&C[(size_t)m * OUTF + o] = v;
    }
}

// ---------------------------------------------------------------------------
// Zin build: Zin[b][0:1024] = lrelu(gnode + bgs), Zin[b][1024:2048] = T_X.
// ---------------------------------------------------------------------------
__global__ __launch_bounds__(256) void zin_build(
    const float* __restrict__ gnode, const float* __restrict__ bgs,
    const float* __restrict__ Tx, float* __restrict__ Zin)
{
    const int idx = blockIdx.x * 256 + threadIdx.x;
    const int b = idx >> 10, o = idx & 1023;
    const float s = gnode[idx] + bgs[0];
    Zin[(size_t)b * 2048 + o] = LRELU(s);
    Zin[(size_t)b * 2048 + 1024 + o] = Tx[idx];
}

// ---------------------------------------------------------------------------
// Z GEMM split-K: grid (16,4,4); chunk kz covers K in [kz*512,(kz+1)*512).
// ---------------------------------------------------------------------------
__global__ __launch_bounds__(256) void gemm_zsplit(
    const float* __restrict__ A, const float* __restrict__ W,
    float* __restrict__ P)
{
    __shared__ float As[16][68];
    __shared__ float Ws[16][68];
    const int tid = threadIdx.x;
    const int tx = tid & 15;
    const int ty = tid >> 4;
    const int m0 = blockIdx.y * 64;
    const int o0 = blockIdx.x * 64;
    const int kbase = blockIdx.z * 512;

    float acc[4][4] = {};
    for (int k0 = kbase; k0 < kbase + 512; k0 += 16) {
        const int j = tid & 15;
        const int i = tid >> 4;
        #pragma unroll
        for (int r = 0; r < 4; ++r)
            As[j][i + 16 * r] = A[(size_t)(m0 + i + 16 * r) * 2048 + k0 + j];
        #pragma unroll
        for (int r = 0; r < 4; ++r)
            Ws[j][i + 16 * r] = W[(size_t)(o0 + i + 16 * r) * 2048 + k0 + j];
        __syncthreads();
        #pragma unroll
        for (int kk = 0; kk < 16; ++kk) {
            const float4 av = *(const float4*)&As[kk][ty * 4];
            const float4 wv = *(const float4*)&Ws[kk][tx * 4];
            const float a[4] = {av.x, av.y, av.z, av.w};
            const float w[4] = {wv.x, wv.y, wv.z, wv.w};
            #pragma unroll
            for (int r = 0; r < 4; ++r)
                #pragma unroll
                for (int c = 0; c < 4; ++c)
                    acc[r][c] += a[r] * w[c];
        }
        __syncthreads();
    }
    float* pz = P + (size_t)blockIdx.z * Bb * OUTF;
    #pragma unroll
    for (int r = 0; r < 4; ++r) {
        const int m = m0 + ty * 4 + r;
        const int o = o0 + tx * 4;
        float4 v;
        float* vp = (float*)&v;
        #pragma unroll
        for (int c = 0; c < 4; ++c) vp[c] = acc[r][c];
        *(float4*)&pz[(size_t)m * OUTF + o] = v;
    }
}

// ---------------------------------------------------------------------------
// Z reduce: C = lrelu(sum_4 P + bzx).
// ---------------------------------------------------------------------------
__global__ __launch_bounds__(256) void zreduce(
    const float* __restrict__ P, const float* __restrict__ bzx,
    float* __restrict__ C)
{
    const int idx = blockIdx.x * 256 + threadIdx.x;
    const int o = idx & 1023;
    const size_t STRIDE = (size_t)Bb * OUTF;
    float s = P[idx] + P[STRIDE + idx] + P[2 * STRIDE + idx] + P[3 * STRIDE + idx]
            + bzx[o];
    C[idx] = LRELU(s);
}

// ---------------------------------------------------------------------------
// nodeatt_soft: s[b,n] = (1/32) * sum_16 spart[(b*131+n)][slot]; softmax; +1.
// ---------------------------------------------------------------------------
__global__ __launch_bounds__(256) void nodeatt_soft(
    const float* __restrict__ spart, float* __restrict__ att)
{
    const int b = blockIdx.x;
    __shared__ float sc[136];
    const int tid = threadIdx.x;
    if (tid < Nn) {
        const float* sp = spart + (size_t)(b * Nn + tid) * 16;
        float s = 0.f;
        #pragma unroll
        for (int i = 0; i < 16; ++i) s += sp[i];
        sc[tid] = s * (1.f / 32.f);
    }
    __syncthreads();
    if (tid < 64) {
        const float v1 = sc[tid];
        const float v2 = sc[tid + 64];
        const float v3 = (tid < 3) ? sc[tid + 128] : -1e30f;
        float m = fmaxf(fmaxf(v1, v2), v3);
        #pragma unroll
        for (int off = 32; off; off >>= 1) m = fmaxf(m, __shfl_xor(m, off));
        const float e1 = expf(v1 - m);
        const float e2 = expf(v2 - m);
        const float e3 = (tid < 3) ? expf(v3 - m) : 0.f;
        float s = e1 + e2 + e3;
        #pragma unroll
        for (int off = 32; off; off >>= 1) s += __shfl_xor(s, off);
        const float inv = 1.f / s;
        float* ab = att + (size_t)b * Nn;
        ab[tid] = e1 * inv + 1.f;
        ab[tid + 64] = e2 * inv + 1.f;
        if (tid < 3) ab[tid + 128] = e3 * inv + 1.f;
    }
}

// ---------------------------------------------------------------------------
// edge_agg (R17 structure + issue-early loads): one block (9 waves) per (b,h).
// ---------------------------------------------------------------------------
__global__ __launch_bounds__(576) void edge_agg(
    const __hip_bfloat16* __restrict__ Gcat, const float* __restrict__ adj,
    const float* __restrict__ att, const __hip_bfloat16* __restrict__ GrawT,
    const float* __restrict__ Wgs, float* __restrict__ edge,
    float* __restrict__ Gout, float* __restrict__ gnode)
{
    __shared__ short SM[25056];
    __shared__ float rsL[144 * 3];
    __shared__ float dxL[Nn], daL[Nn], attL[Nn], wgsL[Nn];

    const int bh = blockIdx.x, b = bh >> 2, h = bh & 3;
    const int tid = threadIdx.x;
    const int lane = tid & 63, wid = tid >> 6;
    const int wr = wid / 3, wc = wid % 3;
    if (tid < Nn) { attL[tid] = att[(size_t)b * Nn + tid]; wgsL[tid] = Wgs[tid]; }

    const short* qb = (const short*)Gcat + (size_t)b * Nn * OC2 + 1024 + h * Dd;
    const short* kb = (const short*)Gcat + (size_t)b * Nn * OC2 + h * Dd;
    const short* gsrcT = (const short*)GrawT + (size_t)bh * 256 * YP;
    const float* adjb = adj + (size_t)b * Nn * Nn;

    int srow = tid >> 2; if (srow > Nn - 1) srow = Nn - 1;
    const int gsrc = ((tid & 3) ^ ((tid >> 3) & 3)) * 8;
    const int dstoff = (tid & ~63) * 8;
    const int cc = lane & 15;
    const int rg = (lane >> 4) * 4;

    // ---- issue-early: adj -> areg (latency folds into QK^T iter-0 waits) ----
    float areg[3][3][4];
    #pragma unroll
    for (int mi = 0; mi < 3; ++mi)
        #pragma unroll
        for (int ni = 0; ni < 3; ++ni) {
            const int y = wc * 48 + ni * 16 + cc;
            #pragma unroll
            for (int r = 0; r < 4; ++r) {
                const int x = wr * 48 + mi * 16 + rg + r;
                areg[mi][ni][r] = (x < Nn && y < Nn) ? adjb[x * Nn + y] : 0.f;
            }
        }

    auto STAGE = [&](int buf, int k0) {
        gload_lds16(qb + (size_t)srow * OC2 + k0 + gsrc, &SM[buf * 4608 + dstoff]);
        gload_lds16(kb + (size_t)srow * OC2 + k0 + gsrc, &SM[9216 + buf * 4608 + dstoff]);
    };

    f32x4 acc[3][3] = {};
    const int sa = ((lane >> 4) ^ ((lane >> 1) & 3)) * 8;

    STAGE(0, 0);
    for (int t = 0; t < 8; ++t) {
        const int buf = t & 1;
        if (t < 7) {
            STAGE(buf ^ 1, (t + 1) * 32);
            asm volatile("s_waitcnt vmcnt(2)" ::: "memory");
        } else {
            asm volatile("s_waitcnt vmcnt(0)" ::: "memory");
        }
        __builtin_amdgcn_s_barrier();
        __builtin_amdgcn_sched_barrier(0);
        bf16x8 qf[3], kf[3];
        #pragma unroll
        for (int i = 0; i < 3; ++i) {
            qf[i] = *(const bf16x8*)&SM[buf * 4608 + (wr * 48 + i * 16 + (lane & 15)) * 32 + sa];
            kf[i] = *(const bf16x8*)&SM[9216 + buf * 4608 + (wc * 48 + i * 16 + (lane & 15)) * 32 + sa];
        }
        __builtin_amdgcn_s_setprio(1);
        #pragma unroll
        for (int mi = 0; mi < 3; ++mi)
            #pragma unroll
            for (int ni = 0; ni < 3; ++ni)
                acc[mi][ni] = __builtin_amdgcn_mfma_f32_16x16x32_bf16(
                    qf[mi], kf[ni], acc[mi][ni], 0, 0, 0);
        __builtin_amdgcn_s_setprio(0);
        __builtin_amdgcn_sched_barrier(0);
        if (t < 7) __builtin_amdgcn_s_barrier();
    }

    // ---- issue-early: GrawT chunk-0 B-fragments (hidden under phase 2/3) ----
    const int brow0 = wid * 32 + (lane & 15);
    const int bcol = (lane >> 4) * 8;
    bf16x8 bcur0, bcur1;
    if (wid < 8) {
        bcur0 = *(const bf16x8*)&gsrcT[(size_t)brow0 * YP + 0 + bcol];
        bcur1 = *(const bf16x8*)&gsrcT[(size_t)(brow0 + 16) * YP + 0 + bcol];
    }

    // phase 2: sigmoid, edge write, slotted rowsums (adj already in areg)
    float* edgeb = edge + (size_t)bh * Nn * Nn;
    #pragma unroll
    for (int mi = 0; mi < 3; ++mi) {
        float rsum[4] = {0.f, 0.f, 0.f, 0.f};
        #pragma unroll
        for (int ni = 0; ni < 3; ++ni) {
            const int y = wc * 48 + ni * 16 + cc;
            #pragma unroll
            for (int r = 0; r < 4; ++r) {
                const int x = wr * 48 + mi * 16 + rg + r;
                const bool in = (x < Nn) && (y < Nn);
                const float e = 1.f / (1.f + __expf(-acc[mi][ni][r] * (1.f / 16.f)));
                acc[mi][ni][r] = e;
                if (in) {
                    edgeb[x * Nn + y] = e;
                    rsum[r] += areg[mi][ni][r] * e;
                }
            }
        }
        #pragma unroll
        for (int r = 0; r < 4; ++r) {
            float v = rsum[r];
            v += __shfl_xor(v, 1); v += __shfl_xor(v, 2);
            v += __shfl_xor(v, 4); v += __shfl_xor(v, 8);
            const int x = wr * 48 + mi * 16 + rg + r;
            if (cc == 0 && x < Nn) rsL[x * 3 + wc] = v;
        }
    }
    __syncthreads();
    if (tid < Nn) {
        const float s = rsL[tid * 3] + rsL[tid * 3 + 1] + rsL[tid * 3 + 2];
        const float dv = rsqrtf(s + 1.f);
        dxL[tid] = dv;
        daL[tid] = dv * attL[tid];
    }
    __syncthreads();   // Qs/Ks dead -> SM reusable as WbL

    // phase 3: Wb -> LDS (stride WLP). Zero y in [131,160).
    short* WbL = SM;
    for (int i = tid; i < 144 * 29; i += 576) {
        const int x = i / 29, y = 131 + i % 29;
        WbL[x * WLP + y] = 0;
    }
    #pragma unroll
    for (int mi = 0; mi < 3; ++mi)
        #pragma unroll
        for (int ni = 0; ni < 3; ++ni) {
            const int y = wc * 48 + ni * 16 + cc;
            #pragma unroll
            for (int r = 0; r < 4; ++r) {
                const int x = wr * 48 + mi * 16 + rg + r;
                if (x < Nn && y < Nn) {
                    float a = areg[mi][ni][r] * acc[mi][ni][r];
                    if (x == y) a += 1.f;
                    const float w = dxL[x] * a * daL[y];
                    __hip_bfloat16 hb = __float2bfloat16(w);
                    WbL[(size_t)x * WLP + y] = *(short*)&hb;
                }
            }
        }
    __syncthreads();

    // phase 4: aggregation MFMA — af from WbL, bfr rolling register prefetch.
    if (wid < 8) {
        f32x4 gacc[9][2] = {};
        #pragma unroll
        for (int kc = 0; kc < 5; ++kc) {
            bf16x8 bnxt0, bnxt1;
            if (kc < 4) {
                bnxt0 = *(const bf16x8*)&gsrcT[(size_t)brow0 * YP + (kc + 1) * 32 + bcol];
                bnxt1 = *(const bf16x8*)&gsrcT[(size_t)(brow0 + 16) * YP + (kc + 1) * 32 + bcol];
            }
            bf16x8 af[9];
            #pragma unroll
            for (int mi = 0; mi < 9; ++mi)
                af[mi] = *(const bf16x8*)&WbL[(mi * 16 + (lane & 15)) * WLP + kc * 32 + (lane >> 4) * 8];
            __builtin_amdgcn_s_setprio(1);
            #pragma unroll
            for (int mi = 0; mi < 9; ++mi) {
                gacc[mi][0] = __builtin_amdgcn_mfma_f32_16x16x32_bf16(
                    af[mi], bcur0, gacc[mi][0], 0, 0, 0);
                gacc[mi][1] = __builtin_amdgcn_mfma_f32_16x16x32_bf16(
                    af[mi], bcur1, gacc[mi][1], 0, 0, 0);
            }
            __builtin_amdgcn_s_setprio(0);
            if (kc < 4) { bcur0 = bnxt0; bcur1 = bnxt1; }
        }

        // phase 5: Gout + gnode colsum (8 waves)
        float* gob = Gout + (size_t)b * Nn * OUTF + h * Dd;
        float gp[2] = {0.f, 0.f};
        #pragma unroll
        for (int mi = 0; mi < 9; ++mi)
            #pragma unroll
            for (int ni = 0; ni < 2; ++ni) {
                const int d = wid * 32 + ni * 16 + (lane & 15);
                #pragma unroll
                for (int r = 0; r < 4; ++r) {
                    const int x = mi * 16 + (lane >> 4) * 4 + r;
                    if (x < Nn) {
                        gob[(size_t)x * OUTF + d] = gacc[mi][ni][r];
                        gp[ni] += wgsL[x] * gacc[mi][ni][r];
                    }
                }
            }
        #pragma unroll
        for (int ni = 0; ni < 2; ++ni) {
            gp[ni] += __shfl_xor(gp[ni], 16);
            gp[ni] += __shfl_xor(gp[ni], 32);
            if (lane < 16)
                gnode[(size_t)b * OUTF + h * Dd + wid * 32 + ni * 16 + lane] = gp[ni];
        }
    }
}

// ---------------------------------------------------------------------------
extern "C" void kernel_launch(void* const* d_in, const int* in_sizes, int n_in,
                              void* d_out, int out_size, void* d_ws, size_t ws_size,
                              hipStream_t stream) {
    const float* tab  = (const float*)d_in[0];
    const float* node = (const float*)d_in[1];
    const float* adj  = (const float*)d_in[2];
    const float* W_gx = (const float*)d_in[3];
    const float* b_gx = (const float*)d_in[4];
    const float* W_tx = (const float*)d_in[5];
    const float* b_tx = (const float*)d_in[6];
    const float* W_gk = (const float*)d_in[7];
    const float* W_tq = (const float*)d_in[8];
    const float* W_gq = (const float*)d_in[9];
    const float* W_gs = (const float*)d_in[10];
    const float* b_gs = (const float*)d_in[11];
    const float* W_zx = (const float*)d_in[12];
    const float* b_zx = (const float*)d_in[13];

    const size_t GX_ELEMS = (size_t)Bb * Nn * OUTF;   // 34,340,864
    const int M_NODE = Bb * Nn;                       // 33536

    float* out   = (float*)d_out;
    float* o_GX  = out;
    float* o_TX  = o_GX + GX_ELEMS;
    float* o_ZX  = o_TX + (size_t)Bb * OUTF;
    float* o_ATT = o_ZX + (size_t)Bb * OUTF;
    float* o_EDG = o_ATT + (size_t)Bb * Nn;

    // workspace: bf16 regions first, then fp32
    __hip_bfloat16* wb      = (__hip_bfloat16*)d_ws;
    __hip_bfloat16* w_nodeb = wb;                                          // 33536*512
    __hip_bfloat16* w_Wcat  = w_nodeb + (size_t)M_NODE * INF_;             // 3072*512
    __hip_bfloat16* w_Gcat  = w_Wcat + (size_t)3072 * INF_;                // 33536*2048
    __hip_bfloat16* w_GrawT = w_Gcat + (size_t)M_NODE * OC2;               // 1024*256*168
    float* wf       = (float*)(w_GrawT + (size_t)Bb * Hh * 256 * YP);
    float* w_Tq     = wf;
    float* w_Zin    = w_Tq + (size_t)Bb * OUTF;                            // 256*2048
    float* w_gnode  = w_Zin + (size_t)Bb * 2 * OUTF;                       // 256*1024
    float* w_spart  = w_gnode + (size_t)Bb * OUTF;                         // 33536*16
    float* w_zpart  = w_spart + (size_t)M_NODE * 16;                       // 4*256*1024

    const dim3 blk(256);

    // 0. fp32 -> bf16 (Wcat = [Wgk | Wgq | Wgx])
    convert_kernel<<<dim3(2048), blk, 0, stream>>>(node, W_gx, W_gk, W_gq,
                                                   w_nodeb, w_Wcat);
    // 1. merged tabular GEMMs (T_X + T_q)
    gemm_tab<<<dim3(32, 4), blk, 0, stream>>>(tab, W_tx, b_tx, W_tq, o_TX, w_Tq);
    // 2. fused node GEMM -> Gcat + GrawT + node-att score partials
    gemm_node_mfma<<<dim3(24, M_NODE / 128), blk, 0, stream>>>(
        w_nodeb, w_Wcat, b_gx, w_Tq, w_Gcat, w_GrawT, w_spart);
    // 3. node attention softmax (from partials) -> o_ATT
    nodeatt_soft<<<dim3(Bb), blk, 0, stream>>>(w_spart, o_ATT);
    // 4. fused edge attention + rowsum + dinv + Wb(LDS) + aggregation + gn
    edge_agg<<<dim3(Bb * Hh), dim3(576), 0, stream>>>(
        w_Gcat, adj, o_ATT, w_GrawT, W_gs, o_EDG, o_GX, w_gnode);
    // 5. Zin build
    zin_build<<<dim3((Bb * OUTF) / 256), blk, 0, stream>>>(w_gnode, b_gs, o_TX, w_Zin);
    // 6. Z GEMM split-K(4) + reduce
    gemm_zsplit<<<dim3(16, 4, 4), blk, 0, stream>>>(w_Zin, W_zx, w_zpart);
    zreduce<<<dim3((Bb * OUTF) / 256), blk, 0, stream>>>(w_zpart, b_zx, o_ZX);
}